// Round 10
// baseline (18.209 us; speedup 1.0000x reference)
//
#include <hip/hip_runtime.h>

#define V 10
#define L 45            // V*(V-1)/2
#define NCOEF 14
#define NSAMP 65536
#define BS 32           // samples per block
#define NTHR 256        // 4 waves -> 8 blocks/CU = 32 waves/CU (full occupancy)
#define LAMP 46         // padded lam row stride

typedef float v4f __attribute__((ext_vector_type(4)));

// col index j for pair l (tril_indices(V, k=-1) row-major order)
__constant__ unsigned char c_col[L] = {
    0,
    0,1,
    0,1,2,
    0,1,2,3,
    0,1,2,3,4,
    0,1,2,3,4,5,
    0,1,2,3,4,5,6,
    0,1,2,3,4,5,6,7,
    0,1,2,3,4,5,6,7,8
};

__global__ __launch_bounds__(NTHR, 8) void decor_fused(
    const float* __restrict__ x, const float* __restrict__ log_d,
    const float* __restrict__ params,
    float* __restrict__ out, float* __restrict__ Mout, float* __restrict__ logd_out,
    float* __restrict__ scal)
{
    __shared__ float ps[NCOEF * L];          // 2.52 KB
    __shared__ float xs[BS * V];             // 1.28 KB
    __shared__ float lam[BS * LAMP];         // 5.89 KB
    __shared__ unsigned char cols[64];

    const int tid = threadIdx.x;
    const int n0  = blockIdx.x * BS;

    // ---- stage params + cols + x tile into LDS (coalesced) ----
    for (int idx = tid; idx < NCOEF * L; idx += NTHR)
        ps[idx] = params[idx];
    if (tid < L) cols[tid] = c_col[tid];
    const v4f* x4 = (const v4f*)(x + (size_t)n0 * V);
    for (int idx = tid; idx < BS * V / 4; idx += NTHR)
        ((v4f*)xs)[idx] = x4[idx];

    // ---- log_d passthrough (float4 copy, through L2/L3) ----
    const v4f* ld4  = (const v4f*)(log_d + (size_t)n0 * V);
    v4f*       ldo4 = (v4f*)(logd_out + (size_t)n0 * V);
    for (int idx = tid; idx < BS * V / 4; idx += NTHR)
        ldo4[idx] = ld4[idx];

    __syncthreads();

    // ---- lambdas: BS*L = 1440 evals, params gathered from LDS ----
    // uniform knots, spacing d = 10/11; u = (x+5)/d + 3
    const float inv_d = 1.1f;
    const float c16   = 1.0f / 6.0f;
    for (int idx = tid; idx < BS * L; idx += NTHR) {
        int nl = idx / L;
        int l  = idx - nl * L;
        float xv = xs[nl * V + cols[l]];
        xv = fminf(fmaxf(xv, -5.0f), 5.0f);
        float u  = (xv + 5.0f) * inv_d + 3.0f;
        int   ii = (int)floorf(u);
        ii = max(3, min(ii, 14));          // ref indicator: x=+5 lands in [t14,t15)
        float f  = u - (float)ii;
        float omf = 1.0f - f;
        float f2 = f * f, f3 = f2 * f;
        float N0 = omf * omf * omf * c16;
        float N1 = (3.0f * f3 - 6.0f * f2 + 4.0f) * c16;
        float N2 = (-3.0f * f3 + 3.0f * f2 + 3.0f * f + 1.0f) * c16;
        float N3 = f3 * c16;               // == 0 when ii==14
        int k0 = ii - 3;
        int k3 = min(k0 + 3, NCOEF - 1);   // B_14 dropped by ref; N3==0 there
        lam[nl * LAMP + l] =
              N0 * ps[(k0    ) * L + l]
            + N1 * ps[(k0 + 1) * L + l]
            + N2 * ps[(k0 + 2) * L + l]
            + N3 * ps[(k3    ) * L + l];
    }
    __syncthreads();

    // ---- assemble + store M (float4) from lam ----
    v4f* M4 = (v4f*)(Mout + (size_t)n0 * V * V);
    for (int idx = tid; idx < BS * 25; idx += NTHR) {
        int nl = idx / 25;
        int q  = idx - nl * 25;
        int e0 = q * 4;
        const float* lr = &lam[nl * LAMP];
        v4f v;
        #pragma unroll
        for (int t = 0; t < 4; ++t) {
            int ee = e0 + t;
            int i  = (ee * 205) >> 11;     // ee/10 for ee<100
            int j  = ee - 10 * i;
            float val;
            if (j > i)       val = 0.0f;
            else if (j == i) val = 1.0f;
            else             val = lr[(i * (i - 1)) / 2 + j];
            v[t] = val;
        }
        M4[idx] = v;
    }

    // ---- out = M @ x (strict-lower + identity), direct coalesced stores ----
    for (int idx = tid; idx < BS * V; idx += NTHR) {
        int nl = idx / V;
        int i  = idx - nl * V;
        float acc = xs[idx];
        const float* lr = &lam[nl * LAMP + (i * (i - 1)) / 2];
        for (int j = 0; j < i; ++j)
            acc += lr[j] * xs[nl * V + j];
        out[(size_t)n0 * V + idx] = acc;
    }

    // ---- ridge scalars: one wave of block 0, params from LDS ----
    if (blockIdx.x == 0 && tid < 64) {
        float s_par = 0.f, s_fir = 0.f, s_sec = 0.f;
        for (int idx = tid; idx < NCOEF * L; idx += 64) {
            int k = idx / L;
            float p0 = ps[idx];
            s_par += p0 * p0;
            if (k + 1 < NCOEF) {
                float p1 = ps[idx + L];
                float d1 = p1 - p0;
                s_fir += d1 * d1;
                if (k + 2 < NCOEF) {
                    float p2 = ps[idx + 2 * L];
                    float d2 = p2 - 2.f * p1 + p0;
                    s_sec += d2 * d2;
                }
            }
        }
        for (int off = 32; off; off >>= 1) {
            s_sec += __shfl_down(s_sec, off);
            s_fir += __shfl_down(s_fir, off);
            s_par += __shfl_down(s_par, off);
        }
        if (tid == 0) { scal[0] = s_sec; scal[1] = s_fir; scal[2] = s_par; }
    }
}

extern "C" void kernel_launch(void* const* d_in, const int* in_sizes, int n_in,
                              void* d_out, int out_size, void* d_ws, size_t ws_size,
                              hipStream_t stream) {
    const float* x      = (const float*)d_in[0];
    const float* log_d  = (const float*)d_in[1];
    const float* params = (const float*)d_in[2];

    float* out      = (float*)d_out;                       // [N, V]
    float* M        = out + (size_t)NSAMP * V;             // [N, V, V]
    float* logd_out = M + (size_t)NSAMP * V * V;           // [N, V]
    float* scal     = logd_out + (size_t)NSAMP * V;        // sec, fir, par

    decor_fused<<<NSAMP / BS, NTHR, 0, stream>>>(x, log_d, params, out, M, logd_out, scal);
}